// Round 20
// baseline (35.952 us; speedup 1.0000x reference)
//
#include <hip/hip_runtime.h>
#include <cstddef>

#define N_ 16
#define L_ 512
#define D_ 256
#define M_ 3584
#define LN_EPS 1e-5f

typedef __attribute__((ext_vector_type(8))) short bf16x8;
typedef __attribute__((ext_vector_type(4))) float f32x4;

__device__ inline unsigned int f2bf_raw(float f) {
    union { float f; unsigned int u; } v; v.f = f;
    return (v.u + 0x7FFFu + ((v.u >> 16) & 1u)) >> 16;   // RNE
}
__device__ inline unsigned int pack2bf(float lo, float hi) {
    return f2bf_raw(lo) | (f2bf_raw(hi) << 16);
}
__device__ inline float bf2f(unsigned int hw) {
    union { unsigned int u; float f; } v; v.u = hw << 16; return v.f;
}
// XOR-swizzled byte offset in the A region (row stride 512 B)
__device__ inline int aswz(int row, int colb) {
    return row * 512 + (((colb & 0x1F0) ^ ((row & 7) << 4)) | (colb & 0xF));
}

// ------------------------------------------------------------------ prep ----
// blocks 0..191: weight fp32 [768 k][256 co] -> fragment-major bf16
// blocks 192..207: per-n cumsum of target -> dense alignment index idx[n][m]
__global__ __launch_bounds__(512)
void prep_kernel(const float* __restrict__ W1, unsigned short* __restrict__ Wt1,
                 const float* __restrict__ W2, unsigned short* __restrict__ Wt2,
                 const int* __restrict__ target, int* __restrict__ idx) {
    __shared__ union { float t[2][32][33]; int s[L_]; } sm;
    const int bid = blockIdx.x;
    if (bid < 192) {
        const int half = threadIdx.x >> 8, st = threadIdx.x & 255;
        const int tile = bid * 2 + half;              // 0..383
        const int kb = (tile % 24) * 32;
        const int cb = ((tile / 24) % 8) * 32;
        const float* W = (tile >= 192) ? W2 : W1;
        unsigned short* Wt = (tile >= 192) ? Wt2 : Wt1;
        const int tx = st & 31, ty = st >> 5;
#pragma unroll
        for (int r = 0; r < 32; r += 8)
            sm.t[half][ty + r][tx] = W[(size_t)(kb + ty + r) * 256 + cb + tx];
        __syncthreads();
        const int jl = st >> 7, l = (st >> 1) & 63, e0 = (st & 1) * 4;
        ushort4 o;
        o.x = (unsigned short)f2bf_raw(sm.t[half][(l >> 4) * 8 + e0 + 0][jl * 16 + (l & 15)]);
        o.y = (unsigned short)f2bf_raw(sm.t[half][(l >> 4) * 8 + e0 + 1][jl * 16 + (l & 15)]);
        o.z = (unsigned short)f2bf_raw(sm.t[half][(l >> 4) * 8 + e0 + 2][jl * 16 + (l & 15)]);
        o.w = (unsigned short)f2bf_raw(sm.t[half][(l >> 4) * 8 + e0 + 3][jl * 16 + (l & 15)]);
        *(ushort4*)(Wt + ((((size_t)(kb >> 5) * 16) + (cb >> 4) + jl) * 64 + l) * 8 + e0) = o;
    } else {
        const int n = bid - 192, t = threadIdx.x;
        const int tv = target[n * L_ + t];            // own duration (in reg)
        sm.s[t] = tv;
        __syncthreads();
        for (int off = 1; off < L_; off <<= 1) {
            int v = (t >= off) ? sm.s[t - off] : 0;
            __syncthreads();
            sm.s[t] += v;
            __syncthreads();
        }
        const int e = sm.s[t], st0 = e - tv;
        const int total = sm.s[L_ - 1];
        int* row = idx + (size_t)n * M_;
        for (int j = st0; j < e; ++j) row[j] = t;     // <=7 scatter writes
        for (int m = total + t; m < M_; m += 512) row[m] = -1;
    }
}

// ------------------------------------------------------ conv K-loop phase ---
// 16-co-strip layout: wave wv owns fragment j = wv (16 co). One coalesced
// 1KB B-load per wave per ks (each weight byte read once per block), 2-step
// reg prefetch, swapped-operand MFMA, NO internal barriers.
template <int NR, int MAXS>
__device__ __forceinline__ void conv_phase(const unsigned char* Ab,
        const unsigned short* __restrict__ Wf,
        int wv, int lane, int fr, int fg, f32x4 (&acc)[NR]) {
    const unsigned short* wb = Wf + ((size_t)wv * 64 + lane) * 8;
    uint4 p0 = *(const uint4*)(wb);                       // ks
    uint4 p1 = *(const uint4*)(wb + 8192);                // ks+1
    for (int ks = 0; ks < 24; ++ks) {
        uint4 q;
        if (ks < 22) q = *(const uint4*)(wb + (size_t)(ks + 2) * 8192);
        const int cib = (ks & 7) * 64 + fg * 16;          // byte col base in A row
        const int koff = ks >> 3;                         // conv tap
        bf16x8 av[NR];
#pragma unroll
        for (int r = 0; r < NR; ++r) {
            int ar = r * 16 + fr + koff;
            if (ar > MAXS) ar = MAXS;                     // clamp (discarded rows)
            av[r] = *(const bf16x8*)(Ab + ar * 512 + (cib ^ ((ar & 7) << 4)));
        }
        bf16x8 bb = *(bf16x8*)&p0;
        __builtin_amdgcn_s_setprio(1);
#pragma unroll
        for (int r = 0; r < NR; ++r)
            acc[r] = __builtin_amdgcn_mfma_f32_16x16x32_bf16(bb, av[r], acc[r], 0, 0, 0);
        __builtin_amdgcn_s_setprio(0);
        p0 = p1; p1 = q;
    }
}

// relu(acc+bias) -> bf16 h rows into A region; lane = 4 consecutive co
// (D[co = wv*16 + fg*4 + q][row = r*16 + fr])
template <int NR, int NROWS>
__device__ __forceinline__ void store_h(unsigned char* Ab, f32x4 (&acc)[NR],
        const float* __restrict__ bias, int wv, int fr, int fg) {
    const int co = wv * 16 + fg * 4;
    const float4 bb = *(const float4*)&bias[co];
#pragma unroll
    for (int r = 0; r < NR; ++r) {
        const int slot = r * 16 + fr;
        if (slot < NROWS) {
            uint2 o;
            o.x = pack2bf(fmaxf(acc[r][0] + bb.x, 0.f), fmaxf(acc[r][1] + bb.y, 0.f));
            o.y = pack2bf(fmaxf(acc[r][2] + bb.z, 0.f), fmaxf(acc[r][3] + bb.w, 0.f));
            *(uint2*)(Ab + aswz(slot, 2 * co)) = o;
        }
    }
}

// ------------------------------------------------------------------ mega ----
// 256 blocks x 1024 threads (1 block/CU). ALL 16 waves (4/SIMD) run every
// phase: gather first (NT writes drain under conv), then stage -> conv1 ->
// LN1 -> conv2 -> LN2+linear. Each wave owns one 16-co fragment strip.
__global__ __launch_bounds__(1024, 4)
void mega_kernel(const float* __restrict__ x,
                 const unsigned short* __restrict__ Wf1,
                 const unsigned short* __restrict__ Wf2,
                 const float* __restrict__ b1, const float* __restrict__ g1,
                 const float* __restrict__ be1,
                 const float* __restrict__ b2, const float* __restrict__ g2,
                 const float* __restrict__ be2,
                 const float* __restrict__ lw, const float* __restrict__ lb,
                 const int* __restrict__ idx,
                 float* __restrict__ out0, float* __restrict__ log_dur) {
    __shared__ unsigned char smA[36 * 512];
    const int tid = threadIdx.x, lane = tid & 63, wv = tid >> 6;
    const int bid = blockIdx.x;
    const int row0 = bid * 32;
    const int n = row0 >> 9, l0 = row0 & 511;
    const int fr = lane & 15, fg = lane >> 4;

    // ---- phase 0: gather 224 mel rows (16 waves x 14 rows); NT stores
    //      drain in the background during the conv phases below.
    {
        const int m0 = (bid & 15) * 224 + wv;    // rows m0 + i*16, i in [0,14)
        const int* ip = idx + (size_t)n * M_ + m0;
        const float* xn = x + (size_t)n * L_ * D_ + lane * 4;
        float* op = out0 + ((size_t)n * M_ + m0) * D_ + lane * 4;
#pragma unroll
        for (int i = 0; i < 14; ++i) {
            const int li = ip[i * 16];
            f32x4 o = {0.f, 0.f, 0.f, 0.f};
            if (li >= 0) o = *(const f32x4*)(xn + (size_t)li * D_);
            __builtin_nontemporal_store(o, (f32x4*)(op + (size_t)i * 16 * D_));
        }
    }

    // ---- stage x once: slots 0..35 <-> l = l0-2+r, bf16, swizzled ----
    for (int i = tid; i < 36 * 64; i += 1024) {
        int r = i >> 6, c4 = i & 63;
        int l = l0 - 2 + r;
        float4 v = {0.f, 0.f, 0.f, 0.f};
        if (l >= 0 && l < L_)
            v = ((const float4*)(x + ((size_t)(n * L_ + l)) * D_))[c4];
        uint2 p;
        p.x = pack2bf(v.x, v.y);
        p.y = pack2bf(v.z, v.w);
        *(uint2*)(smA + aswz(r, c4 * 8)) = p;
    }
    __syncthreads();

    // ---- conv1: h1 slots 0..33 (rows l0-1..l0+32) ----
    f32x4 a1[3];
#pragma unroll
    for (int r = 0; r < 3; ++r) a1[r] = (f32x4){0.f, 0.f, 0.f, 0.f};
    conv_phase<3, 35>(smA, Wf1, wv, lane, fr, fg, a1);
    __syncthreads();                              // all waves done reading x
    store_h<3, 34>(smA, a1, b1, wv, fr, fg);
    __syncthreads();

    // ---- LN1 in place; zero out-of-range rows (exact SAME-pad for conv2) --
    {
        const float4 gv = *(const float4*)&g1[lane * 4];
        const float4 bv = *(const float4*)&be1[lane * 4];
        for (int mm = wv; mm < 34; mm += 16) {
            const int addr = aswz(mm, lane * 8);
            const int hrow = l0 - 1 + mm;
            if (hrow < 0 || hrow >= L_) {
                *(uint2*)(smA + addr) = (uint2){0u, 0u};
                continue;
            }
            uint2 pv = *(uint2*)(smA + addr);
            float v0 = bf2f(pv.x & 0xFFFFu), v1 = bf2f(pv.x >> 16);
            float v2 = bf2f(pv.y & 0xFFFFu), v3 = bf2f(pv.y >> 16);
            float s = v0 + v1 + v2 + v3;
            float ss = v0 * v0 + v1 * v1 + v2 * v2 + v3 * v3;
#pragma unroll
            for (int off = 32; off; off >>= 1) {
                s += __shfl_xor(s, off);
                ss += __shfl_xor(ss, off);
            }
            const float mu = s * (1.f / D_);
            const float var = ss * (1.f / D_) - mu * mu;
            const float rs = rsqrtf(var + LN_EPS);
            uint2 o;
            o.x = pack2bf((v0 - mu) * rs * gv.x + bv.x, (v1 - mu) * rs * gv.y + bv.y);
            o.y = pack2bf((v2 - mu) * rs * gv.z + bv.z, (v3 - mu) * rs * gv.w + bv.w);
            *(uint2*)(smA + addr) = o;
        }
    }
    __syncthreads();

    // ---- conv2: output rows l0..l0+31 from h1 slots 0..33 ----
    f32x4 a2[2];
#pragma unroll
    for (int r = 0; r < 2; ++r) a2[r] = (f32x4){0.f, 0.f, 0.f, 0.f};
    conv_phase<2, 33>(smA, Wf2, wv, lane, fr, fg, a2);
    __syncthreads();                              // done reading h1
    store_h<2, 32>(smA, a2, b2, wv, fr, fg);
    __syncthreads();

    // ---- LN2 + linear -> log_dur ----
    {
        const float4 gv = *(const float4*)&g2[lane * 4];
        const float4 bv = *(const float4*)&be2[lane * 4];
        const float4 wvv = *(const float4*)&lw[lane * 4];
        for (int mm = wv; mm < 32; mm += 16) {
            uint2 pv = *(uint2*)(smA + aswz(mm, lane * 8));
            float v0 = bf2f(pv.x & 0xFFFFu), v1 = bf2f(pv.x >> 16);
            float v2 = bf2f(pv.y & 0xFFFFu), v3 = bf2f(pv.y >> 16);
            float s = v0 + v1 + v2 + v3;
            float ss = v0 * v0 + v1 * v1 + v2 * v2 + v3 * v3;
#pragma unroll
            for (int off = 32; off; off >>= 1) {
                s += __shfl_xor(s, off);
                ss += __shfl_xor(ss, off);
            }
            const float mu = s * (1.f / D_);
            const float var = ss * (1.f / D_) - mu * mu;
            const float rs = rsqrtf(var + LN_EPS);
            float dot = ((v0 - mu) * rs * gv.x + bv.x) * wvv.x
                      + ((v1 - mu) * rs * gv.y + bv.y) * wvv.y
                      + ((v2 - mu) * rs * gv.z + bv.z) * wvv.z
                      + ((v3 - mu) * rs * gv.w + bv.w) * wvv.w;
#pragma unroll
            for (int off = 32; off; off >>= 1) dot += __shfl_xor(dot, off);
            if (lane == 0) log_dur[row0 + mm] = dot + lb[0];
        }
    }
}

// ---------------------------------------------------------------- launch ----
extern "C" void kernel_launch(void* const* d_in, const int* in_sizes, int n_in,
                              void* d_out, int out_size, void* d_ws, size_t ws_size,
                              hipStream_t stream) {
    const float* x   = (const float*)d_in[0];
    const float* w1  = (const float*)d_in[1];
    const float* b1  = (const float*)d_in[2];
    const float* g1  = (const float*)d_in[3];
    const float* be1 = (const float*)d_in[4];
    const float* w2  = (const float*)d_in[5];
    const float* b2  = (const float*)d_in[6];
    const float* g2  = (const float*)d_in[7];
    const float* be2 = (const float*)d_in[8];
    const float* lw  = (const float*)d_in[9];
    const float* lb  = (const float*)d_in[10];
    const int* target = (const int*)d_in[11];

    float* out0 = (float*)d_out;                        // [16, 3584, 256]
    float* log_dur = out0 + (size_t)N_ * M_ * D_;       // [16, 512]

    unsigned short* w1f = (unsigned short*)d_ws;        // [24*16*64*8] bf16
    unsigned short* w2f = w1f + 24 * 8192;              // [24*16*64*8] bf16
    int* idx = (int*)(w2f + 24 * 8192);                 // [16*3584]

    prep_kernel<<<208, 512, 0, stream>>>(w1, w1f, w2, w2f, target, idx);
    mega_kernel<<<256, 1024, 0, stream>>>(x, w1f, w2f, b1, g1, be1,
                                          b2, g2, be2, lw, lb, idx,
                                          out0, log_dur);
}

// Round 21
// 31.102 us; speedup vs baseline: 1.1559x; 1.1559x over previous
//
#include <hip/hip_runtime.h>
#include <cstddef>

#define N_ 16
#define L_ 512
#define D_ 256
#define M_ 3584
#define LN_EPS 1e-5f

typedef __attribute__((ext_vector_type(8))) short bf16x8;
typedef __attribute__((ext_vector_type(4))) float f32x4;

__device__ inline unsigned int f2bf_raw(float f) {
    union { float f; unsigned int u; } v; v.f = f;
    return (v.u + 0x7FFFu + ((v.u >> 16) & 1u)) >> 16;   // RNE
}
__device__ inline unsigned int pack2bf(float lo, float hi) {
    return f2bf_raw(lo) | (f2bf_raw(hi) << 16);
}
__device__ inline float bf2f(unsigned int hw) {
    union { unsigned int u; float f; } v; v.u = hw << 16; return v.f;
}
// XOR-swizzled byte offset in the A region (row stride 512 B)
__device__ inline int aswz(int row, int colb) {
    return row * 512 + (((colb & 0x1F0) ^ ((row & 7) << 4)) | (colb & 0xF));
}

// ------------------------------------------------------------------ prep ----
// blocks 0..191: weight fp32 [768 k][256 co] -> fragment-major bf16
// blocks 192..207: per-n cumsum of target -> dense alignment index idx[n][m]
__global__ __launch_bounds__(512)
void prep_kernel(const float* __restrict__ W1, unsigned short* __restrict__ Wt1,
                 const float* __restrict__ W2, unsigned short* __restrict__ Wt2,
                 const int* __restrict__ target, int* __restrict__ idx) {
    __shared__ union { float t[2][32][33]; int s[L_]; } sm;
    const int bid = blockIdx.x;
    if (bid < 192) {
        const int half = threadIdx.x >> 8, st = threadIdx.x & 255;
        const int tile = bid * 2 + half;              // 0..383
        const int kb = (tile % 24) * 32;
        const int cb = ((tile / 24) % 8) * 32;
        const float* W = (tile >= 192) ? W2 : W1;
        unsigned short* Wt = (tile >= 192) ? Wt2 : Wt1;
        const int tx = st & 31, ty = st >> 5;
#pragma unroll
        for (int r = 0; r < 32; r += 8)
            sm.t[half][ty + r][tx] = W[(size_t)(kb + ty + r) * 256 + cb + tx];
        __syncthreads();
        const int jl = st >> 7, l = (st >> 1) & 63, e0 = (st & 1) * 4;
        ushort4 o;
        o.x = (unsigned short)f2bf_raw(sm.t[half][(l >> 4) * 8 + e0 + 0][jl * 16 + (l & 15)]);
        o.y = (unsigned short)f2bf_raw(sm.t[half][(l >> 4) * 8 + e0 + 1][jl * 16 + (l & 15)]);
        o.z = (unsigned short)f2bf_raw(sm.t[half][(l >> 4) * 8 + e0 + 2][jl * 16 + (l & 15)]);
        o.w = (unsigned short)f2bf_raw(sm.t[half][(l >> 4) * 8 + e0 + 3][jl * 16 + (l & 15)]);
        *(ushort4*)(Wt + ((((size_t)(kb >> 5) * 16) + (cb >> 4) + jl) * 64 + l) * 8 + e0) = o;
    } else {
        const int n = bid - 192, t = threadIdx.x;
        const int tv = target[n * L_ + t];            // own duration (in reg)
        sm.s[t] = tv;
        __syncthreads();
        for (int off = 1; off < L_; off <<= 1) {
            int v = (t >= off) ? sm.s[t - off] : 0;
            __syncthreads();
            sm.s[t] += v;
            __syncthreads();
        }
        const int e = sm.s[t], st0 = e - tv;
        const int total = sm.s[L_ - 1];
        int* row = idx + (size_t)n * M_;
        for (int j = st0; j < e; ++j) row[j] = t;     // <=7 scatter writes
        for (int m = total + t; m < M_; m += 512) row[m] = -1;
    }
}

// relu(acc+bias) -> bf16 h rows into A region; lane = 4 consecutive co
// (16-co-strip: D[co = wv*16 + fg*4 + q][row = r*16 + fr])
template <int NR, int NROWS>
__device__ __forceinline__ void store_h(unsigned char* Ab, f32x4 (&acc)[NR],
        const float* __restrict__ bias, int wv, int fr, int fg) {
    const int co = wv * 16 + fg * 4;
    const float4 bb = *(const float4*)&bias[co];
#pragma unroll
    for (int r = 0; r < NR; ++r) {
        const int slot = r * 16 + fr;
        if (slot < NROWS) {
            uint2 o;
            o.x = pack2bf(fmaxf(acc[r][0] + bb.x, 0.f), fmaxf(acc[r][1] + bb.y, 0.f));
            o.y = pack2bf(fmaxf(acc[r][2] + bb.z, 0.f), fmaxf(acc[r][3] + bb.w, 0.f));
            *(uint2*)(Ab + aswz(slot, 2 * co)) = o;
        }
    }
}

// ------------------------------------------------------------------ mega ----
// 256 blocks x 1024 threads (1 block/CU, 4 waves/SIMD). Each wave owns one
// 16-co fragment strip of the conv AND 14 gather rows. Gather row-copies are
// EMBEDDED in the fully-unrolled conv K-loops (load issued 2 K-steps before
// its NT store) so the vmem pipe streams gather while MFMA+LDS run conv.
__global__ __launch_bounds__(1024, 4)
void mega_kernel(const float* __restrict__ x,
                 const unsigned short* __restrict__ Wf1,
                 const unsigned short* __restrict__ Wf2,
                 const float* __restrict__ b1, const float* __restrict__ g1,
                 const float* __restrict__ be1,
                 const float* __restrict__ b2, const float* __restrict__ g2,
                 const float* __restrict__ be2,
                 const float* __restrict__ lw, const float* __restrict__ lb,
                 const int* __restrict__ idx,
                 float* __restrict__ out0, float* __restrict__ log_dur) {
    __shared__ unsigned char smA[36 * 512];
    const int tid = threadIdx.x, lane = tid & 63, wv = tid >> 6;
    const int bid = blockIdx.x;
    const int row0 = bid * 32;
    const int n = row0 >> 9, l0 = row0 & 511;
    const int fr = lane & 15, fg = lane >> 4;

    // ---- gather state: wave wv owns mel rows m0 + g*16, g in [0,14) ----
    const int m0 = (bid & 15) * 224 + wv;
    const int* ip = idx + (size_t)n * M_ + m0;
    const float* xn = x + (size_t)n * L_ * D_ + lane * 4;
    float* op = out0 + ((size_t)n * M_ + m0) * D_ + lane * 4;
    int li[14];
#pragma unroll
    for (int i = 0; i < 14; ++i) li[i] = ip[i * 16];

    // ---- stage x once: slots 0..35 <-> l = l0-2+r, bf16, swizzled ----
    for (int i = tid; i < 36 * 64; i += 1024) {
        int r = i >> 6, c4 = i & 63;
        int l = l0 - 2 + r;
        float4 v = {0.f, 0.f, 0.f, 0.f};
        if (l >= 0 && l < L_)
            v = ((const float4*)(x + ((size_t)(n * L_ + l)) * D_))[c4];
        uint2 p;
        p.x = pack2bf(v.x, v.y);
        p.y = pack2bf(v.z, v.w);
        *(uint2*)(smA + aswz(r, c4 * 8)) = p;
    }
    __syncthreads();

    // ---- conv1 (h1 slots 0..33) with embedded gather rows 0..11 ----
    f32x4 a1[3];
#pragma unroll
    for (int r = 0; r < 3; ++r) a1[r] = (f32x4){0.f, 0.f, 0.f, 0.f};
    {
        const unsigned short* wb = Wf1 + ((size_t)wv * 64 + lane) * 8;
        uint4 p0 = *(const uint4*)(wb);
        uint4 p1 = *(const uint4*)(wb + 8192);
        f32x4 gcur = {0.f, 0.f, 0.f, 0.f};
        if (li[0] >= 0) gcur = *(const f32x4*)(xn + (size_t)li[0] * D_);
#pragma unroll
        for (int ks = 0; ks < 24; ++ks) {
            uint4 q;
            if (ks < 22) q = *(const uint4*)(wb + (size_t)(ks + 2) * 8192);
            const int cib = (ks & 7) * 64 + fg * 16;
            const int koff = ks >> 3;
            bf16x8 av[3];
#pragma unroll
            for (int r = 0; r < 3; ++r) {
                int ar = r * 16 + fr + koff;
                if (ar > 35) ar = 35;
                av[r] = *(const bf16x8*)(smA + ar * 512 + (cib ^ ((ar & 7) << 4)));
            }
            bf16x8 bb = *(bf16x8*)&p0;
            __builtin_amdgcn_s_setprio(1);
#pragma unroll
            for (int r = 0; r < 3; ++r)
                a1[r] = __builtin_amdgcn_mfma_f32_16x16x32_bf16(bb, av[r], a1[r], 0, 0, 0);
            __builtin_amdgcn_s_setprio(0);
            if (ks & 1) {                         // g = ks>>1 in [0,12)
                const int g = ks >> 1;            // compile-time (full unroll)
                __builtin_nontemporal_store(gcur, (f32x4*)(op + (size_t)g * 16 * D_));
                if (g + 1 < 12) {
                    gcur = (f32x4){0.f, 0.f, 0.f, 0.f};
                    if (li[g + 1] >= 0)
                        gcur = *(const f32x4*)(xn + (size_t)li[g + 1] * D_);
                }
            }
            p0 = p1; p1 = q;
        }
    }
    __syncthreads();                              // all waves done reading x
    store_h<3, 34>(smA, a1, b1, wv, fr, fg);
    __syncthreads();

    // ---- LN1 in place; zero out-of-range rows (exact SAME-pad for conv2) --
    {
        const float4 gv = *(const float4*)&g1[lane * 4];
        const float4 bv = *(const float4*)&be1[lane * 4];
        for (int mm = wv; mm < 34; mm += 16) {
            const int addr = aswz(mm, lane * 8);
            const int hrow = l0 - 1 + mm;
            if (hrow < 0 || hrow >= L_) {
                *(uint2*)(smA + addr) = (uint2){0u, 0u};
                continue;
            }
            uint2 pv = *(uint2*)(smA + addr);
            float v0 = bf2f(pv.x & 0xFFFFu), v1 = bf2f(pv.x >> 16);
            float v2 = bf2f(pv.y & 0xFFFFu), v3 = bf2f(pv.y >> 16);
            float s = v0 + v1 + v2 + v3;
            float ss = v0 * v0 + v1 * v1 + v2 * v2 + v3 * v3;
#pragma unroll
            for (int off = 32; off; off >>= 1) {
                s += __shfl_xor(s, off);
                ss += __shfl_xor(ss, off);
            }
            const float mu = s * (1.f / D_);
            const float var = ss * (1.f / D_) - mu * mu;
            const float rs = rsqrtf(var + LN_EPS);
            uint2 o;
            o.x = pack2bf((v0 - mu) * rs * gv.x + bv.x, (v1 - mu) * rs * gv.y + bv.y);
            o.y = pack2bf((v2 - mu) * rs * gv.z + bv.z, (v3 - mu) * rs * gv.w + bv.w);
            *(uint2*)(smA + addr) = o;
        }
    }
    __syncthreads();

    // ---- conv2 (output rows l0..l0+31) with embedded gather rows 12,13 ----
    f32x4 a2[2];
#pragma unroll
    for (int r = 0; r < 2; ++r) a2[r] = (f32x4){0.f, 0.f, 0.f, 0.f};
    {
        const unsigned short* wb = Wf2 + ((size_t)wv * 64 + lane) * 8;
        uint4 p0 = *(const uint4*)(wb);
        uint4 p1 = *(const uint4*)(wb + 8192);
        f32x4 gcur = {0.f, 0.f, 0.f, 0.f};
        if (li[12] >= 0) gcur = *(const f32x4*)(xn + (size_t)li[12] * D_);
#pragma unroll
        for (int ks = 0; ks < 24; ++ks) {
            uint4 q;
            if (ks < 22) q = *(const uint4*)(wb + (size_t)(ks + 2) * 8192);
            const int cib = (ks & 7) * 64 + fg * 16;
            const int koff = ks >> 3;
            bf16x8 av[2];
#pragma unroll
            for (int r = 0; r < 2; ++r) {
                int ar = r * 16 + fr + koff;
                if (ar > 33) ar = 33;
                av[r] = *(const bf16x8*)(smA + ar * 512 + (cib ^ ((ar & 7) << 4)));
            }
            bf16x8 bb = *(bf16x8*)&p0;
            __builtin_amdgcn_s_setprio(1);
#pragma unroll
            for (int r = 0; r < 2; ++r)
                a2[r] = __builtin_amdgcn_mfma_f32_16x16x32_bf16(bb, av[r], a2[r], 0, 0, 0);
            __builtin_amdgcn_s_setprio(0);
            if (ks == 5) {                        // store row 12, load row 13
                __builtin_nontemporal_store(gcur, (f32x4*)(op + (size_t)12 * 16 * D_));
                gcur = (f32x4){0.f, 0.f, 0.f, 0.f};
                if (li[13] >= 0) gcur = *(const f32x4*)(xn + (size_t)li[13] * D_);
            }
            if (ks == 17) {                       // store row 13
                __builtin_nontemporal_store(gcur, (f32x4*)(op + (size_t)13 * 16 * D_));
            }
            p0 = p1; p1 = q;
        }
    }
    __syncthreads();                              // done reading h1
    store_h<2, 32>(smA, a2, b2, wv, fr, fg);
    __syncthreads();

    // ---- LN2 + linear -> log_dur ----
    {
        const float4 gv = *(const float4*)&g2[lane * 4];
        const float4 bv = *(const float4*)&be2[lane * 4];
        const float4 wvv = *(const float4*)&lw[lane * 4];
        for (int mm = wv; mm < 32; mm += 16) {
            uint2 pv = *(uint2*)(smA + aswz(mm, lane * 8));
            float v0 = bf2f(pv.x & 0xFFFFu), v1 = bf2f(pv.x >> 16);
            float v2 = bf2f(pv.y & 0xFFFFu), v3 = bf2f(pv.y >> 16);
            float s = v0 + v1 + v2 + v3;
            float ss = v0 * v0 + v1 * v1 + v2 * v2 + v3 * v3;
#pragma unroll
            for (int off = 32; off; off >>= 1) {
                s += __shfl_xor(s, off);
                ss += __shfl_xor(ss, off);
            }
            const float mu = s * (1.f / D_);
            const float var = ss * (1.f / D_) - mu * mu;
            const float rs = rsqrtf(var + LN_EPS);
            float dot = ((v0 - mu) * rs * gv.x + bv.x) * wvv.x
                      + ((v1 - mu) * rs * gv.y + bv.y) * wvv.y
                      + ((v2 - mu) * rs * gv.z + bv.z) * wvv.z
                      + ((v3 - mu) * rs * gv.w + bv.w) * wvv.w;
#pragma unroll
            for (int off = 32; off; off >>= 1) dot += __shfl_xor(dot, off);
            if (lane == 0) log_dur[row0 + mm] = dot + lb[0];
        }
    }
}

// ---------------------------------------------------------------- launch ----
extern "C" void kernel_launch(void* const* d_in, const int* in_sizes, int n_in,
                              void* d_out, int out_size, void* d_ws, size_t ws_size,
                              hipStream_t stream) {
    const float* x   = (const float*)d_in[0];
    const float* w1  = (const float*)d_in[1];
    const float* b1  = (const float*)d_in[2];
    const float* g1  = (const float*)d_in[3];
    const float* be1 = (const float*)d_in[4];
    const float* w2  = (const float*)d_in[5];
    const float* b2  = (const float*)d_in[6];
    const float* g2  = (const float*)d_in[7];
    const float* be2 = (const float*)d_in[8];
    const float* lw  = (const float*)d_in[9];
    const float* lb  = (const float*)d_in[10];
    const int* target = (const int*)d_in[11];

    float* out0 = (float*)d_out;                        // [16, 3584, 256]
    float* log_dur = out0 + (size_t)N_ * M_ * D_;       // [16, 512]

    unsigned short* w1f = (unsigned short*)d_ws;        // [24*16*64*8] bf16
    unsigned short* w2f = w1f + 24 * 8192;              // [24*16*64*8] bf16
    int* idx = (int*)(w2f + 24 * 8192);                 // [16*3584]

    prep_kernel<<<208, 512, 0, stream>>>(w1, w1f, w2, w2f, target, idx);
    mega_kernel<<<256, 1024, 0, stream>>>(x, w1f, w2f, b1, g1, be1,
                                          b2, g2, be2, lw, lb, idx,
                                          out0, log_dur);
}

// Round 22
// 30.841 us; speedup vs baseline: 1.1657x; 1.0085x over previous
//
#include <hip/hip_runtime.h>
#include <cstddef>

#define N_ 16
#define L_ 512
#define D_ 256
#define M_ 3584
#define LN_EPS 1e-5f

typedef __attribute__((ext_vector_type(8))) short bf16x8;
typedef __attribute__((ext_vector_type(4))) float f32x4;

__device__ inline unsigned int f2bf_raw(float f) {
    union { float f; unsigned int u; } v; v.f = f;
    return (v.u + 0x7FFFu + ((v.u >> 16) & 1u)) >> 16;   // RNE
}
__device__ inline unsigned int pack2bf(float lo, float hi) {
    return f2bf_raw(lo) | (f2bf_raw(hi) << 16);
}
__device__ inline float bf2f(unsigned int hw) {
    union { unsigned int u; float f; } v; v.u = hw << 16; return v.f;
}
// XOR-swizzled byte offset in the A region (row stride 512 B)
__device__ inline int aswz(int row, int colb) {
    return row * 512 + (((colb & 0x1F0) ^ ((row & 7) << 4)) | (colb & 0xF));
}

// ------------------------------------------------------------------ prep ----
// blocks 0..191: weight fp32 [768 k][256 co] -> fragment-major bf16
// blocks 192..207: per-n cumsum of target -> dense alignment index idx[n][m]
__global__ __launch_bounds__(512)
void prep_kernel(const float* __restrict__ W1, unsigned short* __restrict__ Wt1,
                 const float* __restrict__ W2, unsigned short* __restrict__ Wt2,
                 const int* __restrict__ target, int* __restrict__ idx) {
    __shared__ union { float t[2][32][33]; int s[L_]; } sm;
    const int bid = blockIdx.x;
    if (bid < 192) {
        const int half = threadIdx.x >> 8, st = threadIdx.x & 255;
        const int tile = bid * 2 + half;              // 0..383
        const int kb = (tile % 24) * 32;
        const int cb = ((tile / 24) % 8) * 32;
        const float* W = (tile >= 192) ? W2 : W1;
        unsigned short* Wt = (tile >= 192) ? Wt2 : Wt1;
        const int tx = st & 31, ty = st >> 5;
#pragma unroll
        for (int r = 0; r < 32; r += 8)
            sm.t[half][ty + r][tx] = W[(size_t)(kb + ty + r) * 256 + cb + tx];
        __syncthreads();
        const int jl = st >> 7, l = (st >> 1) & 63, e0 = (st & 1) * 4;
        ushort4 o;
        o.x = (unsigned short)f2bf_raw(sm.t[half][(l >> 4) * 8 + e0 + 0][jl * 16 + (l & 15)]);
        o.y = (unsigned short)f2bf_raw(sm.t[half][(l >> 4) * 8 + e0 + 1][jl * 16 + (l & 15)]);
        o.z = (unsigned short)f2bf_raw(sm.t[half][(l >> 4) * 8 + e0 + 2][jl * 16 + (l & 15)]);
        o.w = (unsigned short)f2bf_raw(sm.t[half][(l >> 4) * 8 + e0 + 3][jl * 16 + (l & 15)]);
        *(ushort4*)(Wt + ((((size_t)(kb >> 5) * 16) + (cb >> 4) + jl) * 64 + l) * 8 + e0) = o;
    } else {
        const int n = bid - 192, t = threadIdx.x;
        const int tv = target[n * L_ + t];            // own duration (in reg)
        sm.s[t] = tv;
        __syncthreads();
        for (int off = 1; off < L_; off <<= 1) {
            int v = (t >= off) ? sm.s[t - off] : 0;
            __syncthreads();
            sm.s[t] += v;
            __syncthreads();
        }
        const int e = sm.s[t], st0 = e - tv;
        const int total = sm.s[L_ - 1];
        int* row = idx + (size_t)n * M_;
        for (int j = st0; j < e; ++j) row[j] = t;     // <=7 scatter writes
        for (int m = total + t; m < M_; m += 512) row[m] = -1;
    }
}

// relu(acc+bias) -> bf16 h rows into A region; lane = 4 consecutive co
// (16-co-strip: D[co = wv*16 + fg*4 + q][row = r*16 + fr])
template <int NR, int NROWS>
__device__ __forceinline__ void store_h(unsigned char* Ab, f32x4 (&acc)[NR],
        const float* __restrict__ bias, int wv, int fr, int fg) {
    const int co = wv * 16 + fg * 4;
    const float4 bb = *(const float4*)&bias[co];
#pragma unroll
    for (int r = 0; r < NR; ++r) {
        const int slot = r * 16 + fr;
        if (slot < NROWS) {
            uint2 o;
            o.x = pack2bf(fmaxf(acc[r][0] + bb.x, 0.f), fmaxf(acc[r][1] + bb.y, 0.f));
            o.y = pack2bf(fmaxf(acc[r][2] + bb.z, 0.f), fmaxf(acc[r][3] + bb.w, 0.f));
            *(uint2*)(Ab + aswz(slot, 2 * co)) = o;
        }
    }
}

// ------------------------------------------------------------------ mega ----
// 256 blocks x 1024 threads (1 block/CU, 4 waves/SIMD). Each wave owns one
// 16-co fragment strip of the conv AND a CONTIGUOUS run of 14 mel rows.
// Contiguous rows share source l (duration runs); li is wave-uniform, so the
// x row is loaded once per run and re-stored from registers -> gather reads
// drop ~3.5x (59MB -> ~17MB), easing the shared per-CU vmem port.
__global__ __launch_bounds__(1024, 4)
void mega_kernel(const float* __restrict__ x,
                 const unsigned short* __restrict__ Wf1,
                 const unsigned short* __restrict__ Wf2,
                 const float* __restrict__ b1, const float* __restrict__ g1,
                 const float* __restrict__ be1,
                 const float* __restrict__ b2, const float* __restrict__ g2,
                 const float* __restrict__ be2,
                 const float* __restrict__ lw, const float* __restrict__ lb,
                 const int* __restrict__ idx,
                 float* __restrict__ out0, float* __restrict__ log_dur) {
    __shared__ unsigned char smA[36 * 512];
    const int tid = threadIdx.x, lane = tid & 63, wv = tid >> 6;
    const int bid = blockIdx.x;
    const int row0 = bid * 32;
    const int n = row0 >> 9, l0 = row0 & 511;
    const int fr = lane & 15, fg = lane >> 4;

    // ---- gather state: wave wv owns contiguous mel rows [m0, m0+14) ----
    const int m0 = (bid & 15) * 224 + wv * 14;
    const int* ip = idx + (size_t)n * M_ + m0;
    const float* xn = x + (size_t)n * L_ * D_ + lane * 4;
    float* op = out0 + ((size_t)n * M_ + m0) * D_ + lane * 4;
    int li[14];
#pragma unroll
    for (int i = 0; i < 14; ++i) li[i] = ip[i];   // wave-uniform values

    // ---- stage x once: slots 0..35 <-> l = l0-2+r, bf16, swizzled ----
    for (int i = tid; i < 36 * 64; i += 1024) {
        int r = i >> 6, c4 = i & 63;
        int l = l0 - 2 + r;
        float4 v = {0.f, 0.f, 0.f, 0.f};
        if (l >= 0 && l < L_)
            v = ((const float4*)(x + ((size_t)(n * L_ + l)) * D_))[c4];
        uint2 p;
        p.x = pack2bf(v.x, v.y);
        p.y = pack2bf(v.z, v.w);
        *(uint2*)(smA + aswz(r, c4 * 8)) = p;
    }
    __syncthreads();

    // ---- conv1 (h1 slots 0..33) with embedded gather rows 0..11 ----
    f32x4 a1[3];
#pragma unroll
    for (int r = 0; r < 3; ++r) a1[r] = (f32x4){0.f, 0.f, 0.f, 0.f};
    {
        const unsigned short* wb = Wf1 + ((size_t)wv * 64 + lane) * 8;
        uint4 p0 = *(const uint4*)(wb);
        uint4 p1 = *(const uint4*)(wb + 8192);
        f32x4 gcur = {0.f, 0.f, 0.f, 0.f};
        if (li[0] >= 0) gcur = *(const f32x4*)(xn + (size_t)li[0] * D_);
#pragma unroll
        for (int ks = 0; ks < 24; ++ks) {
            uint4 q;
            if (ks < 22) q = *(const uint4*)(wb + (size_t)(ks + 2) * 8192);
            const int cib = (ks & 7) * 64 + fg * 16;
            const int koff = ks >> 3;
            bf16x8 av[3];
#pragma unroll
            for (int r = 0; r < 3; ++r) {
                int ar = r * 16 + fr + koff;
                if (ar > 35) ar = 35;
                av[r] = *(const bf16x8*)(smA + ar * 512 + (cib ^ ((ar & 7) << 4)));
            }
            bf16x8 bb = *(bf16x8*)&p0;
            __builtin_amdgcn_s_setprio(1);
#pragma unroll
            for (int r = 0; r < 3; ++r)
                a1[r] = __builtin_amdgcn_mfma_f32_16x16x32_bf16(bb, av[r], a1[r], 0, 0, 0);
            __builtin_amdgcn_s_setprio(0);
            if (ks & 1) {                         // g = ks>>1 in [0,12)
                const int g = ks >> 1;            // compile-time (full unroll)
                __builtin_nontemporal_store(gcur, (f32x4*)(op + (size_t)g * D_));
                if (g + 1 < 12 && li[g + 1] != li[g]) {   // wave-uniform branch
                    gcur = (f32x4){0.f, 0.f, 0.f, 0.f};
                    if (li[g + 1] >= 0)
                        gcur = *(const f32x4*)(xn + (size_t)li[g + 1] * D_);
                }
            }
            p0 = p1; p1 = q;
        }
    }
    __syncthreads();                              // all waves done reading x
    store_h<3, 34>(smA, a1, b1, wv, fr, fg);
    __syncthreads();

    // ---- LN1 in place; zero out-of-range rows (exact SAME-pad for conv2) --
    {
        const float4 gv = *(const float4*)&g1[lane * 4];
        const float4 bv = *(const float4*)&be1[lane * 4];
        for (int mm = wv; mm < 34; mm += 16) {
            const int addr = aswz(mm, lane * 8);
            const int hrow = l0 - 1 + mm;
            if (hrow < 0 || hrow >= L_) {
                *(uint2*)(smA + addr) = (uint2){0u, 0u};
                continue;
            }
            uint2 pv = *(uint2*)(smA + addr);
            float v0 = bf2f(pv.x & 0xFFFFu), v1 = bf2f(pv.x >> 16);
            float v2 = bf2f(pv.y & 0xFFFFu), v3 = bf2f(pv.y >> 16);
            float s = v0 + v1 + v2 + v3;
            float ss = v0 * v0 + v1 * v1 + v2 * v2 + v3 * v3;
#pragma unroll
            for (int off = 32; off; off >>= 1) {
                s += __shfl_xor(s, off);
                ss += __shfl_xor(ss, off);
            }
            const float mu = s * (1.f / D_);
            const float var = ss * (1.f / D_) - mu * mu;
            const float rs = rsqrtf(var + LN_EPS);
            uint2 o;
            o.x = pack2bf((v0 - mu) * rs * gv.x + bv.x, (v1 - mu) * rs * gv.y + bv.y);
            o.y = pack2bf((v2 - mu) * rs * gv.z + bv.z, (v3 - mu) * rs * gv.w + bv.w);
            *(uint2*)(smA + addr) = o;
        }
    }
    __syncthreads();

    // ---- conv2 (output rows l0..l0+31) with embedded gather rows 12,13 ----
    f32x4 a2[2];
#pragma unroll
    for (int r = 0; r < 2; ++r) a2[r] = (f32x4){0.f, 0.f, 0.f, 0.f};
    {
        const unsigned short* wb = Wf2 + ((size_t)wv * 64 + lane) * 8;
        uint4 p0 = *(const uint4*)(wb);
        uint4 p1 = *(const uint4*)(wb + 8192);
        f32x4 gcur = {0.f, 0.f, 0.f, 0.f};
        if (li[12] >= 0) gcur = *(const f32x4*)(xn + (size_t)li[12] * D_);
#pragma unroll
        for (int ks = 0; ks < 24; ++ks) {
            uint4 q;
            if (ks < 22) q = *(const uint4*)(wb + (size_t)(ks + 2) * 8192);
            const int cib = (ks & 7) * 64 + fg * 16;
            const int koff = ks >> 3;
            bf16x8 av[2];
#pragma unroll
            for (int r = 0; r < 2; ++r) {
                int ar = r * 16 + fr + koff;
                if (ar > 33) ar = 33;
                av[r] = *(const bf16x8*)(smA + ar * 512 + (cib ^ ((ar & 7) << 4)));
            }
            bf16x8 bb = *(bf16x8*)&p0;
            __builtin_amdgcn_s_setprio(1);
#pragma unroll
            for (int r = 0; r < 2; ++r)
                a2[r] = __builtin_amdgcn_mfma_f32_16x16x32_bf16(bb, av[r], a2[r], 0, 0, 0);
            __builtin_amdgcn_s_setprio(0);
            if (ks == 5) {                        // store row 12, maybe load 13
                __builtin_nontemporal_store(gcur, (f32x4*)(op + (size_t)12 * D_));
                if (li[13] != li[12]) {
                    gcur = (f32x4){0.f, 0.f, 0.f, 0.f};
                    if (li[13] >= 0) gcur = *(const f32x4*)(xn + (size_t)li[13] * D_);
                }
            }
            if (ks == 17) {                       // store row 13
                __builtin_nontemporal_store(gcur, (f32x4*)(op + (size_t)13 * D_));
            }
            p0 = p1; p1 = q;
        }
    }
    __syncthreads();                              // done reading h1
    store_h<2, 32>(smA, a2, b2, wv, fr, fg);
    __syncthreads();

    // ---- LN2 + linear -> log_dur ----
    {
        const float4 gv = *(const float4*)&g2[lane * 4];
        const float4 bv = *(const float4*)&be2[lane * 4];
        const float4 wvv = *(const float4*)&lw[lane * 4];
        for (int mm = wv; mm < 32; mm += 16) {
            uint2 pv = *(uint2*)(smA + aswz(mm, lane * 8));
            float v0 = bf2f(pv.x & 0xFFFFu), v1 = bf2f(pv.x >> 16);
            float v2 = bf2f(pv.y & 0xFFFFu), v3 = bf2f(pv.y >> 16);
            float s = v0 + v1 + v2 + v3;
            float ss = v0 * v0 + v1 * v1 + v2 * v2 + v3 * v3;
#pragma unroll
            for (int off = 32; off; off >>= 1) {
                s += __shfl_xor(s, off);
                ss += __shfl_xor(ss, off);
            }
            const float mu = s * (1.f / D_);
            const float var = ss * (1.f / D_) - mu * mu;
            const float rs = rsqrtf(var + LN_EPS);
            float dot = ((v0 - mu) * rs * gv.x + bv.x) * wvv.x
                      + ((v1 - mu) * rs * gv.y + bv.y) * wvv.y
                      + ((v2 - mu) * rs * gv.z + bv.z) * wvv.z
                      + ((v3 - mu) * rs * gv.w + bv.w) * wvv.w;
#pragma unroll
            for (int off = 32; off; off >>= 1) dot += __shfl_xor(dot, off);
            if (lane == 0) log_dur[row0 + mm] = dot + lb[0];
        }
    }
}

// ---------------------------------------------------------------- launch ----
extern "C" void kernel_launch(void* const* d_in, const int* in_sizes, int n_in,
                              void* d_out, int out_size, void* d_ws, size_t ws_size,
                              hipStream_t stream) {
    const float* x   = (const float*)d_in[0];
    const float* w1  = (const float*)d_in[1];
    const float* b1  = (const float*)d_in[2];
    const float* g1  = (const float*)d_in[3];
    const float* be1 = (const float*)d_in[4];
    const float* w2  = (const float*)d_in[5];
    const float* b2  = (const float*)d_in[6];
    const float* g2  = (const float*)d_in[7];
    const float* be2 = (const float*)d_in[8];
    const float* lw  = (const float*)d_in[9];
    const float* lb  = (const float*)d_in[10];
    const int* target = (const int*)d_in[11];

    float* out0 = (float*)d_out;                        // [16, 3584, 256]
    float* log_dur = out0 + (size_t)N_ * M_ * D_;       // [16, 512]

    unsigned short* w1f = (unsigned short*)d_ws;        // [24*16*64*8] bf16
    unsigned short* w2f = w1f + 24 * 8192;              // [24*16*64*8] bf16
    int* idx = (int*)(w2f + 24 * 8192);                 // [16*3584]

    prep_kernel<<<208, 512, 0, stream>>>(w1, w1f, w2, w2f, target, idx);
    mega_kernel<<<256, 1024, 0, stream>>>(x, w1f, w2f, b1, g1, be1,
                                          b2, g2, be2, lw, lb, idx,
                                          out0, log_dur);
}